// Round 2
// baseline (106.840 us; speedup 1.0000x reference)
//
#include <hip/hip_runtime.h>
#include <math.h>

#define D 40
#define NN 1024
#define BB 2

// tanh-approx gelu (GPT-2 style), max abs err vs exact ~3e-4.
// g = 0.5*a*(1 + tanh(0.79788456*(a + 0.044715*a^3)))
// tanh(z) = 1 - 2/(exp(2z)+1); exp(2z) = exp2(2z*log2(e))
__device__ __forceinline__ float gelu_tanh(float a) {
    float u = a * a;
    float z = a * fmaf(0.0356774081f, u, 0.7978845608f);   // 0.79788456*a + 0.035677*a^3
    float e = __builtin_amdgcn_exp2f(z * 2.885390082f);    // e^{2z}
    float r = __builtin_amdgcn_rcpf(e + 1.0f);
    float t = fmaf(-2.0f, r, 1.0f);                        // tanh(z)
    float ha = 0.5f * a;
    return fmaf(ha, t, ha);
}

// ai = x @ W1[:D] + b1, aj = x @ W1[D:]
__global__ __launch_bounds__(64) void precompute_kernel(
    const float* __restrict__ x, const float* __restrict__ W1,
    const float* __restrict__ b1, float* __restrict__ ai, float* __restrict__ aj) {
    int r = blockIdx.x;   // 0..B*N-1
    int t = threadIdx.x;  // 64
    __shared__ float xr[D];
    if (t < D) xr[t] = x[(size_t)r * D + t];
    __syncthreads();
    if (t < D) {
        float s1 = b1[t];
        float s2 = 0.0f;
#pragma unroll
        for (int k = 0; k < D; ++k) {
            float xv = xr[k];
            s1 = fmaf(xv, W1[k * D + t], s1);
            s2 = fmaf(xv, W1[(D + k) * D + t], s2);
        }
        ai[(size_t)r * D + t] = s1;
        aj[(size_t)r * D + t] = s2;
    }
}

__global__ __launch_bounds__(256, 3) void pair_kernel(
    const float* __restrict__ ai_g, const float* __restrict__ aj_g,
    const float* __restrict__ W2, const float* __restrict__ b2,
    float* __restrict__ out) {
    __shared__ float lds_a[256 * 41];  // staged aj rows (stride 41), reused as reduction buf
    __shared__ float sm[256];

    const int t = threadIdx.x;
    const int bid = blockIdx.x;
    const int b = bid & 1;
    const int i = NN - 1 - (bid >> 1);  // big rows dispatched first

    const float* __restrict__ ai_row = ai_g + ((size_t)b * NN + i) * D;  // uniform

    float m = 0.0f, l = 0.0f;
    float o[D];
#pragma unroll
    for (int d = 0; d < D; ++d) o[d] = 0.0f;

    const int nwin = (i + 256) >> 8;  // ceil((i+1)/256)
    for (int w = 0; w < nwin; ++w) {
        const int jbase = w << 8;
        // ---- stage 256 aj rows (source row clamped to i -> always finite) ----
#pragma unroll
        for (int s = 0; s < 10; ++s) {
            int idx4 = t + (s << 8);            // 0..2559 (row-quads)
            int row = (idx4 * 6554) >> 16;      // idx4 / 10 exactly on this range
            int col = (idx4 - row * 10) << 2;   // multiple of 4
            int jsrc = jbase + row;
            if (jsrc > i) jsrc = i;
            const float4 v = *reinterpret_cast<const float4*>(
                aj_g + ((size_t)b * NN + jsrc) * D + col);
            float* dst = lds_a + row * 41 + col;
            dst[0] = v.x; dst[1] = v.y; dst[2] = v.z; dst[3] = v.w;
        }
        __syncthreads();

        const int j = jbase + t;
        const bool valid = (j <= i);
        const float* arow = lds_a + t * 41;

        float p[D];
        {   // k = 0, fused with the b2 init
            float h0 = gelu_tanh(ai_row[0] + arow[0]);
#pragma unroll
            for (int d = 0; d < D; ++d) p[d] = fmaf(h0, W2[d], b2[d]);
        }
#pragma unroll 3
        for (int k = 1; k < D; ++k) {
            float hk = gelu_tanh(ai_row[k] + arow[k]);
#pragma unroll
            for (int d = 0; d < D; ++d) p[d] = fmaf(hk, W2[k * D + d], p[d]);
        }
        float sq = 0.0f;
#pragma unroll
        for (int d = 0; d < D; ++d) sq = fmaf(p[d], p[d], sq);
        float s = sqrtf(sq);

        // online softmax update (branch-free, masked lanes contribute 0)
        float sv = valid ? s : 0.0f;
        float mn = fmaxf(m, sv);
        float scale = __expf(m - mn);        // == 1.0 exactly when mn == m
        float wgt = valid ? __expf(s - mn) : 0.0f;
        l = fmaf(l, scale, wgt);
#pragma unroll
        for (int d = 0; d < D; ++d) o[d] = fmaf(o[d], scale, wgt * p[d]);
        m = mn;
        __syncthreads();
    }

    // ---- merge 256 online-softmax states ----
    sm[t] = m;
    __syncthreads();
    for (int off = 128; off > 0; off >>= 1) {
        if (t < off) sm[t] = fmaxf(sm[t], sm[t + off]);
        __syncthreads();
    }
    const float M = sm[0];
    __syncthreads();
    const float c = __expf(m - M);
    float* row = lds_a + t * 41;
#pragma unroll
    for (int d = 0; d < D; ++d) row[d] = o[d] * c;
    row[D] = l * c;
    __syncthreads();
    for (int off = 128; off > 0; off >>= 1) {
        if (t < off) {
            float* a_ = lds_a + t * 41;
            const float* b_ = lds_a + (t + off) * 41;
#pragma unroll
            for (int d = 0; d <= D; ++d) a_[d] += b_[d];
        }
        __syncthreads();
    }
    if (t < D) {
        out[((size_t)b * NN + i) * D + t] = lds_a[t] / lds_a[D];
    }
}

extern "C" void kernel_launch(void* const* d_in, const int* in_sizes, int n_in,
                              void* d_out, int out_size, void* d_ws, size_t ws_size,
                              hipStream_t stream) {
    const float* x  = (const float*)d_in[0];
    const float* W1 = (const float*)d_in[1];
    const float* b1 = (const float*)d_in[2];
    const float* W2 = (const float*)d_in[3];
    const float* b2 = (const float*)d_in[4];
    float* out = (float*)d_out;

    float* ai = (float*)d_ws;            // B*N*D floats
    float* aj = ai + (size_t)BB * NN * D;

    precompute_kernel<<<BB * NN, 64, 0, stream>>>(x, W1, b1, ai, aj);
    pair_kernel<<<BB * NN, 256, 0, stream>>>(ai, aj, W2, b2, out);
}

// Round 3
// 73.850 us; speedup vs baseline: 1.4467x; 1.4467x over previous
//
#include <hip/hip_runtime.h>
#include <math.h>

#define D 40
#define NN 1024
#define BB 2
#define WIN 128
#define RS 36              // LDS row stride in dwords (72 bf16 slots = 144 B)
#define HDW (WIN * RS)     // dwords per h array (hi or lo)

typedef __attribute__((ext_vector_type(8))) short bf16x8;
typedef __attribute__((ext_vector_type(4))) float f32x4;

__device__ __forceinline__ unsigned short f2bf(float x) {
    unsigned int u = __float_as_uint(x);
    u += 0x7fff + ((u >> 16) & 1);          // RNE
    return (unsigned short)(u >> 16);
}
__device__ __forceinline__ float bf2f(unsigned short b) {
    return __uint_as_float(((unsigned int)b) << 16);
}

__device__ __forceinline__ float gelu_tanh(float a) {
    float u = a * a;
    float z = a * fmaf(0.0356774081f, u, 0.7978845608f);
    float e = __builtin_amdgcn_exp2f(z * 2.885390082f);    // e^{2z}
    float r = __builtin_amdgcn_rcpf(e + 1.0f);
    float t = fmaf(-2.0f, r, 1.0f);                        // tanh(z)
    float ha = 0.5f * a;
    return fmaf(ha, t, ha);
}

// ai = x @ W1[:D] + b1, aj = x @ W1[D:]
__global__ __launch_bounds__(64) void precompute_kernel(
    const float* __restrict__ x, const float* __restrict__ W1,
    const float* __restrict__ b1, float* __restrict__ ai, float* __restrict__ aj) {
    int r = blockIdx.x;
    int t = threadIdx.x;
    __shared__ float xr[D];
    if (t < D) xr[t] = x[(size_t)r * D + t];
    __syncthreads();
    if (t < D) {
        float s1 = b1[t];
        float s2 = 0.0f;
#pragma unroll
        for (int k = 0; k < D; ++k) {
            float xv = xr[k];
            s1 = fmaf(xv, W1[k * D + t], s1);
            s2 = fmaf(xv, W1[(D + k) * D + t], s2);
        }
        ai[(size_t)r * D + t] = s1;
        aj[(size_t)r * D + t] = s2;
    }
}

__global__ __launch_bounds__(256) void pair_kernel(
    const float* __restrict__ ai_g, const float* __restrict__ aj_g,
    const float* __restrict__ W2, const float* __restrict__ b2,
    float* __restrict__ out) {
    __shared__ unsigned int lds_u[2 * HDW];   // h_hi tile | h_lo tile (36 KB)

    const int t = threadIdx.x;
    const int bid = blockIdx.x;
    const int bb = bid & 1;
    const int i = NN - 1 - (bid >> 1);        // big rows first
    const int w = t >> 6;                     // wave id 0..3
    const int l = t & 63;
    const int lr = l & 15;
    const int lg = l >> 4;

    // ---- one-time: W2 -> LDS coalesced, then gather bf16x2 B-fragments ----
    for (int idx = t; idx < D * D; idx += 256)
        lds_u[idx] = __float_as_uint(W2[idx]);
    __syncthreads();

    bf16x8 bh[3][2], bl[3][2];
    {
        const float* w2l = (const float*)lds_u;
#pragma unroll
        for (int nt = 0; nt < 3; ++nt)
#pragma unroll
            for (int kt = 0; kt < 2; ++kt)
#pragma unroll
                for (int e = 0; e < 8; ++e) {
                    int k = kt * 32 + lg * 8 + e;     // B: k = 8*(l>>4)+e
                    int dd = nt * 16 + lr;            // B: col = l&15
                    float v = (k < D && dd < D) ? w2l[k * D + dd] : 0.0f;
                    unsigned short hi = f2bf(v);
                    unsigned short lo = f2bf(v - bf2f(hi));
                    bh[nt][kt][e] = (short)hi;
                    bl[nt][kt][e] = (short)lo;
                }
    }
    __syncthreads();

    // zero LDS once (k = 40..63 pad region must stay zero)
    for (int idx = t; idx < 2 * HDW; idx += 256) lds_u[idx] = 0u;

    float bv[3];
    bv[0] = b2[lr];
    bv[1] = b2[16 + lr];
    bv[2] = (lr < 8) ? b2[32 + lr] : 0.0f;

    const float* __restrict__ ai_row = ai_g + ((size_t)bb * NN + i) * D;

    // staging mapping: two lanes per j, each handles 20 k's
    const int jl = t & 127;
    const int kh = t >> 7;                    // 0 -> k0..19, 1 -> k20..39
    unsigned int* hb = lds_u + jl * RS;
    unsigned int* lb = lds_u + HDW + jl * RS;
    const float* air = ai_row + kh * 20;

    float m_run = 0.0f, l_run = 0.0f;
    float o0 = 0.0f, o1 = 0.0f, o2 = 0.0f;

    const int nwin = (i + WIN) >> 7;          // ceil((i+1)/128)
    __syncthreads();                          // zeroing done before first stage

    for (int win = 0; win < nwin; ++win) {
        const int jbase = win << 7;

        // ---- stage: h = gelu(ai + aj) -> bf16 hi/lo rows in LDS ----
        {
            const int jsrc = min(jbase + jl, i);
            const float* ajr = aj_g + ((size_t)bb * NN + jsrc) * D + kh * 20;
            unsigned int hw[10], lw[10];
#pragma unroll
            for (int q = 0; q < 5; ++q) {
                const float4 v = *reinterpret_cast<const float4*>(ajr + q * 4);
                float h0 = gelu_tanh(air[q * 4 + 0] + v.x);
                float h1 = gelu_tanh(air[q * 4 + 1] + v.y);
                float h2 = gelu_tanh(air[q * 4 + 2] + v.z);
                float h3 = gelu_tanh(air[q * 4 + 3] + v.w);
                unsigned short a0 = f2bf(h0), a1 = f2bf(h1), a2 = f2bf(h2), a3 = f2bf(h3);
                hw[2 * q]     = (unsigned int)a0 | ((unsigned int)a1 << 16);
                hw[2 * q + 1] = (unsigned int)a2 | ((unsigned int)a3 << 16);
                unsigned short r0 = f2bf(h0 - bf2f(a0)), r1 = f2bf(h1 - bf2f(a1));
                unsigned short r2 = f2bf(h2 - bf2f(a2)), r3 = f2bf(h3 - bf2f(a3));
                lw[2 * q]     = (unsigned int)r0 | ((unsigned int)r1 << 16);
                lw[2 * q + 1] = (unsigned int)r2 | ((unsigned int)r3 << 16);
            }
            if (kh == 0) {
                *reinterpret_cast<uint4*>(hb + 0) = make_uint4(hw[0], hw[1], hw[2], hw[3]);
                *reinterpret_cast<uint4*>(hb + 4) = make_uint4(hw[4], hw[5], hw[6], hw[7]);
                *reinterpret_cast<uint2*>(hb + 8) = make_uint2(hw[8], hw[9]);
                *reinterpret_cast<uint4*>(lb + 0) = make_uint4(lw[0], lw[1], lw[2], lw[3]);
                *reinterpret_cast<uint4*>(lb + 4) = make_uint4(lw[4], lw[5], lw[6], lw[7]);
                *reinterpret_cast<uint2*>(lb + 8) = make_uint2(lw[8], lw[9]);
            } else {
                *reinterpret_cast<uint2*>(hb + 10) = make_uint2(hw[0], hw[1]);
                *reinterpret_cast<uint4*>(hb + 12) = make_uint4(hw[2], hw[3], hw[4], hw[5]);
                *reinterpret_cast<uint4*>(hb + 16) = make_uint4(hw[6], hw[7], hw[8], hw[9]);
                *reinterpret_cast<uint2*>(lb + 10) = make_uint2(lw[0], lw[1]);
                *reinterpret_cast<uint4*>(lb + 12) = make_uint4(lw[2], lw[3], lw[4], lw[5]);
                *reinterpret_cast<uint4*>(lb + 16) = make_uint4(lw[6], lw[7], lw[8], lw[9]);
            }
        }
        __syncthreads();

        // ---- MFMA: p = h @ W2 (bf16x2 split: hh + hl + lh) ----
        f32x4 acc[2][3];
#pragma unroll
        for (int m = 0; m < 2; ++m)
#pragma unroll
            for (int nt = 0; nt < 3; ++nt)
                acc[m][nt] = (f32x4){0.0f, 0.0f, 0.0f, 0.0f};

#pragma unroll
        for (int m = 0; m < 2; ++m) {
            const int row = (w * 2 + m) * 16 + lr;            // A: row = l&15
            const unsigned int* pA = lds_u + row * RS + lg * 4; // A: k = 8*(l>>4)+e
#pragma unroll
            for (int kt = 0; kt < 2; ++kt) {
                bf16x8 ah = __builtin_bit_cast(bf16x8,
                    *reinterpret_cast<const uint4*>(pA + kt * 16));
                bf16x8 al = __builtin_bit_cast(bf16x8,
                    *reinterpret_cast<const uint4*>(pA + HDW + kt * 16));
#pragma unroll
                for (int nt = 0; nt < 3; ++nt) {
                    acc[m][nt] = __builtin_amdgcn_mfma_f32_16x16x32_bf16(ah, bh[nt][kt], acc[m][nt], 0, 0, 0);
                    acc[m][nt] = __builtin_amdgcn_mfma_f32_16x16x32_bf16(ah, bl[nt][kt], acc[m][nt], 0, 0, 0);
                    acc[m][nt] = __builtin_amdgcn_mfma_f32_16x16x32_bf16(al, bh[nt][kt], acc[m][nt], 0, 0, 0);
                }
            }
        }

        // ---- ||p||, online softmax, o accumulation ----
        float sv[2][4];
#pragma unroll
        for (int m = 0; m < 2; ++m)
#pragma unroll
            for (int r = 0; r < 4; ++r) {
                float p0 = acc[m][0][r] + bv[0];
                float p1 = acc[m][1][r] + bv[1];
                float p2 = acc[m][2][r] + bv[2];
                acc[m][0][r] = p0; acc[m][1][r] = p1; acc[m][2][r] = p2;
                float sq = fmaf(p0, p0, fmaf(p1, p1, p2 * p2));
                sq += __shfl_xor(sq, 1);
                sq += __shfl_xor(sq, 2);
                sq += __shfl_xor(sq, 4);
                sq += __shfl_xor(sq, 8);
                int j = jbase + (w * 2 + m) * 16 + lg * 4 + r;  // C: row=(l>>4)*4+r
                sv[m][r] = (j <= i) ? sqrtf(sq) : -1e30f;
            }
        float mx = fmaxf(fmaxf(fmaxf(sv[0][0], sv[0][1]), fmaxf(sv[0][2], sv[0][3])),
                         fmaxf(fmaxf(sv[1][0], sv[1][1]), fmaxf(sv[1][2], sv[1][3])));
        mx = fmaxf(mx, __shfl_xor(mx, 16));
        mx = fmaxf(mx, __shfl_xor(mx, 32));
        float mnew = fmaxf(m_run, mx);
        float scale = __expf(m_run - mnew);
        m_run = mnew;
        float wsum = 0.0f, oa0 = 0.0f, oa1 = 0.0f, oa2 = 0.0f;
#pragma unroll
        for (int m = 0; m < 2; ++m)
#pragma unroll
            for (int r = 0; r < 4; ++r) {
                float wgt = __expf(sv[m][r] - mnew);   // invalid j -> exactly 0
                wsum += wgt;
                oa0 = fmaf(wgt, acc[m][0][r], oa0);
                oa1 = fmaf(wgt, acc[m][1][r], oa1);
                oa2 = fmaf(wgt, acc[m][2][r], oa2);
            }
        l_run = fmaf(l_run, scale, wsum);
        o0 = fmaf(o0, scale, oa0);
        o1 = fmaf(o1, scale, oa1);
        o2 = fmaf(o2, scale, oa2);
        __syncthreads();
    }

    // ---- reduce across lane subgroups, then merge 4 waves via LDS ----
    o0 += __shfl_xor(o0, 16); o0 += __shfl_xor(o0, 32);
    o1 += __shfl_xor(o1, 16); o1 += __shfl_xor(o1, 32);
    o2 += __shfl_xor(o2, 16); o2 += __shfl_xor(o2, 32);
    l_run += __shfl_xor(l_run, 16); l_run += __shfl_xor(l_run, 32);

    float* mbuf = (float*)lds_u;
    if (l < 16) {
        mbuf[w * 48 + lr] = o0;
        mbuf[w * 48 + 16 + lr] = o1;
        if (lr < 8) mbuf[w * 48 + 32 + lr] = o2;
        if (lr == 0) { mbuf[w * 48 + 40] = l_run; mbuf[w * 48 + 41] = m_run; }
    }
    __syncthreads();
    if (t < D) {
        float M = fmaxf(fmaxf(mbuf[41], mbuf[48 + 41]),
                        fmaxf(mbuf[96 + 41], mbuf[144 + 41]));
        float L = 0.0f, val = 0.0f;
#pragma unroll
        for (int ww = 0; ww < 4; ++ww) {
            float c = __expf(mbuf[ww * 48 + 41] - M);
            L = fmaf(c, mbuf[ww * 48 + 40], L);
            val = fmaf(c, mbuf[ww * 48 + t], val);
        }
        out[((size_t)bb * NN + i) * D + t] = val / L;
    }
}

extern "C" void kernel_launch(void* const* d_in, const int* in_sizes, int n_in,
                              void* d_out, int out_size, void* d_ws, size_t ws_size,
                              hipStream_t stream) {
    const float* x  = (const float*)d_in[0];
    const float* W1 = (const float*)d_in[1];
    const float* b1 = (const float*)d_in[2];
    const float* W2 = (const float*)d_in[3];
    const float* b2 = (const float*)d_in[4];
    float* out = (float*)d_out;

    float* ai = (float*)d_ws;            // B*N*D floats
    float* aj = ai + (size_t)BB * NN * D;

    precompute_kernel<<<BB * NN, 64, 0, stream>>>(x, W1, b1, ai, aj);
    pair_kernel<<<BB * NN, 256, 0, stream>>>(ai, aj, W2, b2, out);
}

// Round 4
// 47.980 us; speedup vs baseline: 2.2267x; 1.5392x over previous
//
#include <hip/hip_runtime.h>
#include <math.h>

#define D 40
#define NN 1024
#define BB 2
#define WIN 128
#define RSH 20              // dwords per h row (40 fp16, 80 B)
#define HBUF 2576           // 128*20 + 16 zeroed pad dwords

typedef __attribute__((ext_vector_type(8))) _Float16 f16x8;
typedef __attribute__((ext_vector_type(4))) float f32x4;

__device__ __forceinline__ unsigned int pk16(float a, float b) {
    return __builtin_bit_cast(unsigned int, __builtin_amdgcn_cvt_pkrtz(a, b));
}

__device__ __forceinline__ float gelu_tanh(float a) {
    float u = a * a;
    float z = a * fmaf(0.0356774081f, u, 0.7978845608f);
    float e = __builtin_amdgcn_exp2f(z * 2.885390082f);    // e^{2z}
    float r = __builtin_amdgcn_rcpf(e + 1.0f);
    float t = fmaf(-2.0f, r, 1.0f);                        // tanh(z)
    float ha = 0.5f * a;
    return fmaf(ha, t, ha);
}

// ai = x @ W1[:D] + b1, aj = x @ W1[D:]; block 0 also packs W2 fp16 MFMA fragments
__global__ __launch_bounds__(64) void precompute_kernel(
    const float* __restrict__ x, const float* __restrict__ W1,
    const float* __restrict__ b1, const float* __restrict__ W2,
    float* __restrict__ ai, float* __restrict__ aj, uint4* __restrict__ w2f) {
    int r = blockIdx.x;
    int t = threadIdx.x;
    __shared__ float xr[D];
    if (t < D) xr[t] = x[(size_t)r * D + t];
    __syncthreads();
    if (t < D) {
        float s1 = b1[t];
        float s2 = 0.0f;
#pragma unroll
        for (int k = 0; k < D; ++k) {
            float xv = xr[k];
            s1 = fmaf(xv, W1[k * D + t], s1);
            s2 = fmaf(xv, W1[(D + k) * D + t], s2);
        }
        ai[(size_t)r * D + t] = s1;
        aj[(size_t)r * D + t] = s2;
    }
    if (r == 0) {
        // pack W2 into per-lane fp16 B-fragments: col = l&15, k = kt*32 + (l>>4)*8 + e
        const int lr = t & 15, lg = t >> 4;
#pragma unroll
        for (int nt = 0; nt < 3; ++nt)
#pragma unroll
            for (int kt = 0; kt < 2; ++kt) {
                unsigned int u[4];
#pragma unroll
                for (int pe = 0; pe < 4; ++pe) {
                    int k0 = kt * 32 + lg * 8 + pe * 2;
                    int dd = nt * 16 + lr;
                    float v0 = (k0 < D && dd < D) ? W2[k0 * D + dd] : 0.0f;
                    float v1 = (k0 + 1 < D && dd < D) ? W2[(k0 + 1) * D + dd] : 0.0f;
                    u[pe] = pk16(v0, v1);
                }
                w2f[(nt * 2 + kt) * 64 + t] = make_uint4(u[0], u[1], u[2], u[3]);
            }
    }
}

__global__ __launch_bounds__(256) void pair_kernel(
    const float* __restrict__ ai_g, const float* __restrict__ aj_g,
    const uint4* __restrict__ w2f, const float* __restrict__ b2,
    float* __restrict__ out) {
    __shared__ unsigned int lds[2 * HBUF];    // double-buffered fp16 h tile (20.6 KB)

    const int t = threadIdx.x;
    const int bid = blockIdx.x;
    const int bb = bid & 1;
    const int i = NN - 1 - (bid >> 1);        // big rows first
    const int w = t >> 6;
    const int l = t & 63;
    const int lr = l & 15;
    const int lg = l >> 4;

    // zero the 16-dword guard tails (read by kt=1 spill of row 127)
    if (t < 16) { lds[128 * RSH + t] = 0u; lds[HBUF + 128 * RSH + t] = 0u; }

    // W2 fragments: 6 x uint4 per lane
    f16x8 bfr[3][2];
#pragma unroll
    for (int nt = 0; nt < 3; ++nt)
#pragma unroll
        for (int kt = 0; kt < 2; ++kt)
            bfr[nt][kt] = __builtin_bit_cast(f16x8, w2f[(nt * 2 + kt) * 64 + l]);

    float bv[3];
    bv[0] = b2[lr];
    bv[1] = b2[16 + lr];
    bv[2] = (lr < 8) ? b2[32 + lr] : 0.0f;

    const float* __restrict__ ai_row = ai_g + ((size_t)bb * NN + i) * D;
    const int jl = t & 127;                   // j within window
    const int kh = t >> 7;                    // 0: k0..19, 1: k20..39
    float air[20];
#pragma unroll
    for (int q = 0; q < 20; ++q) air[q] = ai_row[kh * 20 + q];

    float m_run = 0.0f, l_run = 0.0f;
    float o0 = 0.0f, o1 = 0.0f, o2 = 0.0f;

    const int nwin = (i + WIN) >> 7;

    auto stage = [&](int win, int buf) {
        const int jsrc = min((win << 7) + jl, i);
        const float* ajr = aj_g + ((size_t)bb * NN + jsrc) * D + kh * 20;
        unsigned int hw[10];
#pragma unroll
        for (int q = 0; q < 5; ++q) {
            const float4 v = *reinterpret_cast<const float4*>(ajr + q * 4);
            float h0 = gelu_tanh(air[q * 4 + 0] + v.x);
            float h1 = gelu_tanh(air[q * 4 + 1] + v.y);
            float h2 = gelu_tanh(air[q * 4 + 2] + v.z);
            float h3 = gelu_tanh(air[q * 4 + 3] + v.w);
            hw[2 * q]     = pk16(h0, h1);
            hw[2 * q + 1] = pk16(h2, h3);
        }
        unsigned int* hb = lds + buf * HBUF + jl * RSH + kh * 10;
        if (kh == 0) {
            *reinterpret_cast<uint4*>(hb + 0) = make_uint4(hw[0], hw[1], hw[2], hw[3]);
            *reinterpret_cast<uint4*>(hb + 4) = make_uint4(hw[4], hw[5], hw[6], hw[7]);
            *reinterpret_cast<uint2*>(hb + 8) = make_uint2(hw[8], hw[9]);
        } else {
            *reinterpret_cast<uint2*>(hb + 0) = make_uint2(hw[0], hw[1]);
            *reinterpret_cast<uint4*>(hb + 2) = make_uint4(hw[2], hw[3], hw[4], hw[5]);
            *reinterpret_cast<uint4*>(hb + 6) = make_uint4(hw[6], hw[7], hw[8], hw[9]);
        }
    };

    stage(0, 0);
    __syncthreads();

    for (int win = 0; win < nwin; ++win) {
        const int cur = win & 1;
        const int jbase = win << 7;
        if (win + 1 < nwin) stage(win + 1, cur ^ 1);

        // ---- MFMA: p = h @ W2 (single-pass fp16) ----
        f32x4 acc[2][3];
#pragma unroll
        for (int m = 0; m < 2; ++m)
#pragma unroll
            for (int nt = 0; nt < 3; ++nt)
                acc[m][nt] = (f32x4){0.0f, 0.0f, 0.0f, 0.0f};
        const unsigned int* hbase = lds + cur * HBUF;
#pragma unroll
        for (int m = 0; m < 2; ++m) {
            const unsigned int* pA = hbase + ((w * 2 + m) * 16 + lr) * RSH + lg * 4;
#pragma unroll
            for (int kt = 0; kt < 2; ++kt) {
                f16x8 a = __builtin_bit_cast(f16x8,
                    *reinterpret_cast<const uint4*>(pA + kt * 16));
#pragma unroll
                for (int nt = 0; nt < 3; ++nt)
                    acc[m][nt] = __builtin_amdgcn_mfma_f32_16x16x32_f16(a, bfr[nt][kt], acc[m][nt], 0, 0, 0);
            }
        }

        // ---- ||p||, online softmax, o accumulation ----
        float sv[2][4];
#pragma unroll
        for (int m = 0; m < 2; ++m)
#pragma unroll
            for (int r = 0; r < 4; ++r) {
                float p0 = acc[m][0][r] + bv[0];
                float p1 = acc[m][1][r] + bv[1];
                float p2 = acc[m][2][r] + bv[2];
                acc[m][0][r] = p0; acc[m][1][r] = p1; acc[m][2][r] = p2;
                float sq = fmaf(p0, p0, fmaf(p1, p1, p2 * p2));
                sq += __shfl_xor(sq, 1);
                sq += __shfl_xor(sq, 2);
                sq += __shfl_xor(sq, 4);
                sq += __shfl_xor(sq, 8);
                int j = jbase + (w * 2 + m) * 16 + lg * 4 + r;
                sv[m][r] = (j <= i) ? sqrtf(sq) : -1e30f;
            }
        float mx = fmaxf(fmaxf(fmaxf(sv[0][0], sv[0][1]), fmaxf(sv[0][2], sv[0][3])),
                         fmaxf(fmaxf(sv[1][0], sv[1][1]), fmaxf(sv[1][2], sv[1][3])));
        mx = fmaxf(mx, __shfl_xor(mx, 16));
        mx = fmaxf(mx, __shfl_xor(mx, 32));
        float mnew = fmaxf(m_run, mx);
        float scale = __expf(m_run - mnew);
        m_run = mnew;
        float wsum = 0.0f, oa0 = 0.0f, oa1 = 0.0f, oa2 = 0.0f;
#pragma unroll
        for (int m = 0; m < 2; ++m)
#pragma unroll
            for (int r = 0; r < 4; ++r) {
                float wgt = __expf(sv[m][r] - mnew);   // masked j -> exactly 0
                wsum += wgt;
                oa0 = fmaf(wgt, acc[m][0][r], oa0);
                oa1 = fmaf(wgt, acc[m][1][r], oa1);
                oa2 = fmaf(wgt, acc[m][2][r], oa2);
            }
        l_run = fmaf(l_run, scale, wsum);
        o0 = fmaf(o0, scale, oa0);
        o1 = fmaf(o1, scale, oa1);
        o2 = fmaf(o2, scale, oa2);
        __syncthreads();
    }

    // ---- reduce across lane subgroups, then merge 4 waves via LDS ----
    o0 += __shfl_xor(o0, 16); o0 += __shfl_xor(o0, 32);
    o1 += __shfl_xor(o1, 16); o1 += __shfl_xor(o1, 32);
    o2 += __shfl_xor(o2, 16); o2 += __shfl_xor(o2, 32);
    l_run += __shfl_xor(l_run, 16); l_run += __shfl_xor(l_run, 32);

    float* mbuf = (float*)lds;
    if (l < 16) {
        mbuf[w * 48 + lr] = o0;
        mbuf[w * 48 + 16 + lr] = o1;
        if (lr < 8) mbuf[w * 48 + 32 + lr] = o2;
        if (lr == 0) { mbuf[w * 48 + 40] = l_run; mbuf[w * 48 + 41] = m_run; }
    }
    __syncthreads();
    if (t < D) {
        float M = fmaxf(fmaxf(mbuf[41], mbuf[48 + 41]),
                        fmaxf(mbuf[96 + 41], mbuf[144 + 41]));
        float L = 0.0f, val = 0.0f;
#pragma unroll
        for (int ww = 0; ww < 4; ++ww) {
            float c = __expf(mbuf[ww * 48 + 41] - M);
            L = fmaf(c, mbuf[ww * 48 + 40], L);
            val = fmaf(c, mbuf[ww * 48 + t], val);
        }
        out[((size_t)bb * NN + i) * D + t] = val / L;
    }
}

extern "C" void kernel_launch(void* const* d_in, const int* in_sizes, int n_in,
                              void* d_out, int out_size, void* d_ws, size_t ws_size,
                              hipStream_t stream) {
    const float* x  = (const float*)d_in[0];
    const float* W1 = (const float*)d_in[1];
    const float* b1 = (const float*)d_in[2];
    const float* W2 = (const float*)d_in[3];
    const float* b2 = (const float*)d_in[4];
    float* out = (float*)d_out;

    float* ai = (float*)d_ws;                      // B*N*D floats
    float* aj = ai + (size_t)BB * NN * D;          // B*N*D floats
    uint4* w2f = (uint4*)(aj + (size_t)BB * NN * D);  // 6*64 uint4 (6 KB)

    precompute_kernel<<<BB * NN, 64, 0, stream>>>(x, W1, b1, W2, ai, aj, w2f);
    pair_kernel<<<BB * NN, 256, 0, stream>>>(ai, aj, w2f, b2, out);
}